// Round 4
// baseline (323.831 us; speedup 1.0000x reference)
//
#include <hip/hip_runtime.h>

#define INV_T 14.285714285714286f  // 1/0.07
#define C1 0.055803571428571425f   // INV_T / 256 (undoes the 16x-per-input fp8 scale)

typedef float f32x16 __attribute__((ext_vector_type(16)));
typedef long i64x2 __attribute__((ext_vector_type(2)));

__device__ __forceinline__ unsigned char f2e4m3(float f) {
    unsigned char s = (unsigned char)((__float_as_uint(f) >> 24) & 0x80);
    float a = fabsf(f);
    if (a > 448.f) a = 448.f;
    if (a == 0.f) return s;
    int e = (int)((__float_as_uint(a) >> 23) & 0xFF) - 127;
    if (e < -10) return s;
    if (e < -6) e = -6;
    float scale = __int_as_float((unsigned)(130 - e) << 23);  // 2^(3-e)
    int mi = (int)rintf(a * scale);
    if (mi >= 16) { mi >>= 1; ++e; }
    if (mi < 8) return s | (unsigned char)mi;                  // subnormal (e==-6)
    return s | (unsigned char)(((e + 7) << 3) | (mi - 8));
}

__device__ __forceinline__ void async16(void* l, const void* g) {
    __builtin_amdgcn_global_load_lds(
        (const __attribute__((address_space(1))) unsigned int*)g,
        (__attribute__((address_space(3))) unsigned int*)l, 16, 0, 0);
}

// ---- merged: fp32->fp8(x16) convert + per-row distance/Sp/counts ----
__global__ void __launch_bounds__(256) k_prep(const float* __restrict__ emb,
                                              const float* __restrict__ center,
                                              const int* __restrict__ labels,
                                              unsigned char* __restrict__ embQ,
                                              float* __restrict__ out,
                                              float* __restrict__ Sp,
                                              int* __restrict__ cnt, int D) {
    int i = blockIdx.x;
    int tid = threadIdx.x;
    const float4* row = (const float4*)(emb + (size_t)i * D);
    const float4* c4 = (const float4*)center;
    float4 e = row[tid];
    float4 c = c4[tid];
    if (embQ)
        ((uchar4*)(embQ + (size_t)i * D))[tid] =
            make_uchar4(f2e4m3(e.x * 16.f), f2e4m3(e.y * 16.f),
                        f2e4m3(e.z * 16.f), f2e4m3(e.w * 16.f));
    float dx = e.x - c.x, dy = e.y - c.y, dz = e.z - c.z, dw = e.w - c.w;
    float d2 = dx * dx + dy * dy + dz * dz + dw * dw;
    float sp = e.x * c.x + e.y * c.y + e.z * c.z + e.w * c.w;
#pragma unroll
    for (int m = 1; m <= 32; m <<= 1) {
        d2 += __shfl_xor(d2, m, 64);
        sp += __shfl_xor(sp, m, 64);
    }
    __shared__ float sd2[4], ssp[4];
    int wave = tid >> 6;
    if ((tid & 63) == 0) { sd2[wave] = d2; ssp[wave] = sp; }
    __syncthreads();
    if (tid == 0) {
        float dd = sd2[0] + sd2[1] + sd2[2] + sd2[3];
        float ss = ssp[0] + ssp[1] + ssp[2] + ssp[3];
        out[5 + i] = sqrtf(dd);
        Sp[i] = ss * INV_T;
        atomicAdd(&cnt[labels[i] == 0 ? 0 : 1], 1);
    }
}

// ---- s_m[d] = sum over machine rows of emb[:,d] ----
__global__ void __launch_bounds__(256) k_colsum(const float* __restrict__ emb,
                                                const int* __restrict__ labels,
                                                float* __restrict__ s_m, int D) {
    int t = threadIdx.x;
    int r0 = blockIdx.x * 32;
    float4 acc = {0.f, 0.f, 0.f, 0.f};
#pragma unroll 4
    for (int r = 0; r < 32; ++r) {
        float sc = (labels[r0 + r] == 0) ? 1.f : 0.f;
        float4 v = ((const float4*)(emb + (size_t)(r0 + r) * D))[t];
        acc.x += v.x * sc; acc.y += v.y * sc; acc.z += v.z * sc; acc.w += v.w * sc;
    }
    atomicAdd(&s_m[t * 4 + 0], acc.x);
    atomicAdd(&s_m[t * 4 + 1], acc.y);
    atomicAdd(&s_m[t * 4 + 2], acc.z);
    atomicAdd(&s_m[t * 4 + 3], acc.w);
}

// ---- sumexp[i] += sum_{j != i} exp((S_ij - 1)/T), fp8 MFMA, dbuf K-loop ----
// 256x128 tiles (rows x cols) over strict-upper pairs; 8 waves of 64x64
// (2x2 frags of 32x32x16_fp8_fp8). LDS c-major: slot = c*NR + row (16B chunks)
// -> lane-contiguous conflict-free ds_read_b128. Double-buffered with raw
// s_barrier + fine vmcnt so prefetch stays in flight across compute.
template <bool PRE>
__global__ void __launch_bounds__(512, 4)
k_sumexp8(const unsigned char* __restrict__ embQ, const float* __restrict__ embF,
          float* __restrict__ sumexp, int D, int nRT) {
    int bid = blockIdx.x;
    int M = 2 * nRT + 1;
    float mf = (float)M;
    int R = (int)((mf - sqrtf(fmaxf(mf * mf - 4.0f * (float)bid, 0.f))) * 0.5f);
    if (R < 0) R = 0;
    if (R > nRT - 1) R = nRT - 1;
    while (R + 1 <= nRT - 1 && (R + 1) * (M - (R + 1)) <= bid) ++R;
    while (R > 0 && R * (M - R) > bid) --R;
    int C = 2 * R + (bid - R * (M - R));
    int rowbase = R * 256, colbase = C * 128;

    int tid = threadIdx.x;
    int wave = tid >> 6, lane = tid & 63;
    int wr = wave >> 1, wc = wave & 1;   // wave tile: rows [wr*64,+64), cols [wc*64,+64)
    int l31 = lane & 31, kk = lane >> 5;

    __shared__ unsigned char sA[2][16384];  // 256 rows x 4 chunks, c-major
    __shared__ unsigned char sB[2][8192];   // 128 rows x 4 chunks, c-major
    __shared__ float rred[2][256];
    __shared__ float cred[4][128];

    f32x16 acc[2][2];
#pragma unroll
    for (int fr = 0; fr < 2; ++fr)
#pragma unroll
        for (int fc = 0; fc < 2; ++fc)
#pragma unroll
            for (int v = 0; v < 16; ++v) acc[fr][fc][v] = 0.f;

    // staging thread-constants: 2 A-chunks + 1 B-chunk per thread per K-tile
    int sa0 = tid, sa1 = 512 + tid, sb0 = tid;
    int ra0 = sa0 & 255, ca0 = sa0 >> 8;
    int ra1 = sa1 & 255, ca1 = sa1 >> 8;
    int rb0 = sb0 & 127, cb0 = sb0 >> 7;
    const unsigned char* gA0q = PRE ? embQ + (size_t)(rowbase + ra0) * D + ca0 * 16 : nullptr;
    const unsigned char* gA1q = PRE ? embQ + (size_t)(rowbase + ra1) * D + ca1 * 16 : nullptr;
    const unsigned char* gB0q = PRE ? embQ + (size_t)(colbase + rb0) * D + cb0 * 16 : nullptr;

    const int kIters = D >> 6;

    auto stageF = [&](int buf, int kt, int rrow, int cc, int slot, bool isA) {
        const float* src = embF + (size_t)((isA ? rowbase : colbase) + rrow) * D + kt * 64 + cc * 16;
        unsigned int w[4];
#pragma unroll
        for (int p = 0; p < 4; ++p) {
            float4 f = ((const float4*)src)[p];
            w[p] = (unsigned)f2e4m3(f.x * 16.f) | ((unsigned)f2e4m3(f.y * 16.f) << 8) |
                   ((unsigned)f2e4m3(f.z * 16.f) << 16) | ((unsigned)f2e4m3(f.w * 16.f) << 24);
        }
        uint4 pk = make_uint4(w[0], w[1], w[2], w[3]);
        if (isA) *(uint4*)&sA[buf][slot * 16] = pk;
        else     *(uint4*)&sB[buf][slot * 16] = pk;
    };

    auto stage = [&](int buf, int kt) {
        if constexpr (PRE) {
            int ko = kt * 64;
            async16(&sA[buf][sa0 * 16], gA0q + ko);
            async16(&sA[buf][sa1 * 16], gA1q + ko);
            async16(&sB[buf][sb0 * 16], gB0q + ko);
        } else {
            stageF(buf, kt, ra0, ca0, sa0, true);
            stageF(buf, kt, ra1, ca1, sa1, true);
            stageF(buf, kt, rb0, cb0, sb0, false);
        }
    };

    stage(0, 0);
    for (int kt = 0; kt < kIters; ++kt) {
        int cur = kt & 1;
        bool more = (kt + 1 < kIters);
        if (more) stage(cur ^ 1, kt + 1);
        if constexpr (PRE) {
            if (more) asm volatile("s_waitcnt vmcnt(3)" ::: "memory");
            else      asm volatile("s_waitcnt vmcnt(0)" ::: "memory");
            asm volatile("s_barrier" ::: "memory");
        } else {
            __syncthreads();
        }
        const unsigned char* A = sA[cur];
        const unsigned char* Bp = sB[cur];
#pragma unroll
        for (int t2 = 0; t2 < 2; ++t2) {
            i64x2 av[2], bv[2];
#pragma unroll
            for (int fr = 0; fr < 2; ++fr)
                av[fr] = *(const i64x2*)&A[((((t2 * 2 + kk) << 8) + wr * 64 + fr * 32 + l31)) * 16];
#pragma unroll
            for (int fc = 0; fc < 2; ++fc)
                bv[fc] = *(const i64x2*)&Bp[((((t2 * 2 + kk) << 7) + wc * 64 + fc * 32 + l31)) * 16];
#pragma unroll
            for (int j = 0; j < 2; ++j)
#pragma unroll
                for (int fr = 0; fr < 2; ++fr)
#pragma unroll
                    for (int fc = 0; fc < 2; ++fc)
                        acc[fr][fc] = __builtin_amdgcn_mfma_f32_32x32x16_fp8_fp8(
                            av[fr][j], bv[fc][j], acc[fr][fc], 0, 0, 0);
        }
        if constexpr (PRE) {
            asm volatile("s_waitcnt lgkmcnt(0)" ::: "memory");  // ds_reads done before buffer reuse
            asm volatile("s_barrier" ::: "memory");
        } else {
            __syncthreads();
        }
    }

    // epilogue: exp over strictly-upper elements + row/col reductions
    float rs[2][16];
    float cs[2] = {0.f, 0.f};
#pragma unroll
    for (int fr = 0; fr < 2; ++fr)
#pragma unroll
        for (int v = 0; v < 16; ++v) rs[fr][v] = 0.f;

#pragma unroll
    for (int fr = 0; fr < 2; ++fr)
#pragma unroll
        for (int fc = 0; fc < 2; ++fc) {
            int gcol = colbase + wc * 64 + fc * 32 + l31;
#pragma unroll
            for (int v = 0; v < 16; ++v) {
                int grow = rowbase + wr * 64 + fr * 32 + (v & 3) + 8 * (v >> 2) + 4 * kk;
                float e = (grow < gcol) ? __expf(acc[fr][fc][v] * C1 - INV_T) : 0.f;
                rs[fr][v] += e;
                cs[fc] += e;
            }
        }

#pragma unroll
    for (int m = 1; m <= 16; m <<= 1)
#pragma unroll
        for (int fr = 0; fr < 2; ++fr)
#pragma unroll
            for (int v = 0; v < 16; ++v) rs[fr][v] += __shfl_xor(rs[fr][v], m, 64);
    if (l31 == 0)
#pragma unroll
        for (int fr = 0; fr < 2; ++fr)
#pragma unroll
            for (int v = 0; v < 16; ++v)
                rred[wc][wr * 64 + fr * 32 + (v & 3) + 8 * (v >> 2) + 4 * kk] = rs[fr][v];

#pragma unroll
    for (int fc = 0; fc < 2; ++fc) cs[fc] += __shfl_xor(cs[fc], 32, 64);
    if (kk == 0)
#pragma unroll
        for (int fc = 0; fc < 2; ++fc) cred[wr][wc * 64 + fc * 32 + l31] = cs[fc];

    __syncthreads();
    if (tid < 256) {
        atomicAdd(&sumexp[rowbase + tid], rred[0][tid] + rred[1][tid]);
    } else if (tid < 384) {
        int u = tid - 256;
        atomicAdd(&sumexp[colbase + u], cred[0][u] + cred[1][u] + cred[2][u] + cred[3][u]);
    }
}

// ---- per-row finalize ----
__global__ void __launch_bounds__(256) k_finalize(const float* __restrict__ emb,
                                                  const float* __restrict__ s_m,
                                                  const float* __restrict__ Sp,
                                                  const float* __restrict__ sumexp,
                                                  const int* __restrict__ labels,
                                                  const float* __restrict__ outv,
                                                  const float* __restrict__ rmp,
                                                  const float* __restrict__ rhp,
                                                  float* __restrict__ scal, int D) {
    int tid = threadIdx.x;
    int wave = tid >> 6, lane = tid & 63;
    __shared__ float ac[8];
    if (tid < 8) ac[tid] = 0.f;
    __syncthreads();
    float rm = rmp[0], rh = rhp[0];
    const float4* sm4 = (const float4*)s_m;
    for (int it = 0; it < 8; ++it) {
        int i = blockIdx.x * 32 + it * 4 + wave;
        const float4* row = (const float4*)(emb + (size_t)i * D);
        float q = 0.f, sd = 0.f;
#pragma unroll
        for (int j = 0; j < 4; ++j) {
            float4 e = row[lane * 4 + j];
            float4 s = sm4[lane * 4 + j];
            q += e.x * s.x + e.y * s.y + e.z * s.z + e.w * s.w;
            sd += e.x * e.x + e.y * e.y + e.z * e.z + e.w * e.w;
        }
#pragma unroll
        for (int m = 1; m <= 32; m <<= 1) {
            q += __shfl_xor(q, m, 64);
            sd += __shfl_xor(sd, m, 64);
        }
        if (lane == 0) {
            float LP = Sp[i];
            float eS = __expf(LP - INV_T);
            float lse = INV_T + __logf(sumexp[i] + eS);
            bool mach = (labels[i] == 0);
            float pos = (q - (mach ? sd : 0.f)) * INV_T + LP;
            float d = outv[5 + i];
            atomicAdd(&ac[2], eS);
            if (mach) {
                atomicAdd(&ac[4], lse);
                atomicAdd(&ac[5], pos);
                atomicAdd(&ac[3], LP);
                float x = d - rm;
                if (x > 0.f) atomicAdd(&ac[0], x * x);
            } else {
                float x = rh - d;
                if (x > 0.f) atomicAdd(&ac[1], x * x);
            }
        }
    }
    __syncthreads();
    if (tid < 8) atomicAdd(&scal[tid], ac[tid]);
}

// ---- combine scalars ----
__global__ void k_final(const float* __restrict__ scal, const int* __restrict__ cnt,
                        float* __restrict__ out) {
    if (threadIdx.x == 0) {
        int nm = cnt[0], nh = cnt[1];
        float nmf = (float)(nm > 1 ? nm : 1);
        float nhf = (float)(nh > 1 ? nh : 1);
        float loss_m = scal[0] / nmf;
        float loss_h = scal[1] / nhf;
        float loss_shell = loss_m + loss_h;
        float lse_p = INV_T + __logf(scal[2]);
        float proto = lse_p - scal[3] / nmf;
        float con = scal[4] - scal[5] / nmf;
        int denom = (nm + 1 > 1) ? nm + 1 : 1;
        float lc = (con + proto) / (float)denom;
        if (!(nm > 0 && nh > 0)) lc = 0.f;
        out[0] = loss_shell + lc;
        out[1] = loss_shell;
        out[2] = loss_m;
        out[3] = loss_h;
        out[4] = lc;
    }
}

extern "C" void kernel_launch(void* const* d_in, const int* in_sizes, int n_in,
                              void* d_out, int out_size, void* d_ws, size_t ws_size,
                              hipStream_t stream) {
    const float* emb = (const float*)d_in[0];
    const float* center = (const float*)d_in[1];
    const float* rmp = (const float*)d_in[2];
    const float* rhp = (const float*)d_in[3];
    const int* labels = (const int*)d_in[4];
    float* out = (float*)d_out;
    const int B = in_sizes[4];
    const int D = in_sizes[1];

    size_t qBytes = (size_t)B * D;  // fp8 copy
    size_t auxBytes = (size_t)B * 4 + (size_t)D * 4 + 256 + (size_t)B * 4;
    bool pre = ws_size >= qBytes + auxBytes;
    size_t Z0 = pre ? qBytes : 0;

    char* ws = (char*)d_ws;
    unsigned char* embQ = (unsigned char*)ws;
    float* sumexp = (float*)(ws + Z0);
    float* s_m = (float*)(ws + Z0 + (size_t)B * 4);
    float* scal = (float*)(ws + Z0 + (size_t)B * 4 + (size_t)D * 4);
    int* cnt = (int*)(scal + 8);
    float* Sp = (float*)(ws + Z0 + (size_t)B * 4 + (size_t)D * 4 + 256);

    hipMemsetAsync(ws + Z0, 0, (size_t)B * 4 + (size_t)D * 4 + 256, stream);

    k_prep<<<B, D / 4, 0, stream>>>(emb, center, labels, pre ? embQ : nullptr, out, Sp, cnt, D);
    k_colsum<<<B / 32, D / 4, 0, stream>>>(emb, labels, s_m, D);

    int nRT = B / 256;
    int nBlocks = nRT * (nRT + 1);  // pairs (R<=C') over 256-row x 128-col tiles
    if (pre) k_sumexp8<true><<<nBlocks, 512, 0, stream>>>(embQ, nullptr, sumexp, D, nRT);
    else     k_sumexp8<false><<<nBlocks, 512, 0, stream>>>(nullptr, emb, sumexp, D, nRT);

    k_finalize<<<B / 32, 256, 0, stream>>>(emb, s_m, Sp, sumexp, labels, out, rmp, rhp, scal, D);
    k_final<<<1, 64, 0, stream>>>(scal, cnt, out);
}